// Round 1
// baseline (1292.993 us; speedup 1.0000x reference)
//
#include <hip/hip_runtime.h>
#include <stdint.h>

// LSTM2Encoder: x=emb[ids]; h0=lstm0(x); h1=lstm1(h0); out=relu(h1@Wlin^T+b)
// All GEMMs via bf16 hi/lo 3-product split MFMA (fp32-accurate), gate rows
// permuted to (i,f,g,o)-interleaved so activations fuse in the GEMM epilogue.

typedef unsigned short ushort_t;
typedef __attribute__((ext_vector_type(8))) short short8;
typedef __attribute__((ext_vector_type(4))) float float4v;
typedef __attribute__((ext_vector_type(4))) unsigned int uint4v;
typedef __attribute__((ext_vector_type(2))) unsigned int uint2v;

__device__ __forceinline__ ushort_t f2bf(float x) {
  union { float f; unsigned int u; } a; a.f = x;
  unsigned int r = a.u + 0x7fffu + ((a.u >> 16) & 1u);
  return (ushort_t)(r >> 16);
}
__device__ __forceinline__ float bf2f(ushort_t h) {
  union { unsigned int u; float f; } a; a.u = ((unsigned int)h) << 16;
  return a.f;
}
__device__ __forceinline__ float sigmoidf_(float x) { return 1.0f / (1.0f + __expf(-x)); }
__device__ __forceinline__ float tanhf_(float x) { return 1.0f - 2.0f / (__expf(2.0f * x) + 1.0f); }

__device__ __forceinline__ void gl2lds16(const void* g, void* l) {
  __builtin_amdgcn_global_load_lds(
      (const __attribute__((address_space(1))) void*)g,
      (__attribute__((address_space(3))) void*)l, 16, 0, 0);
}

// ---------------- prep: permute+split weights, fold biases -----------------
// W'[4j+g][k] = W[g*512+j][k]  (g in {i,f,g,o});  b'[4j+g] = b_ih[n]+b_hh[n]
__global__ __launch_bounds__(256) void prep_kernel(
    const float* __restrict__ W0, const float* __restrict__ bi0, const float* __restrict__ bh0,
    const float* __restrict__ W1, const float* __restrict__ bi1, const float* __restrict__ bh1,
    const float* __restrict__ WL,
    ushort_t* __restrict__ W0h, ushort_t* __restrict__ W0l,
    ushort_t* __restrict__ W1h, ushort_t* __restrict__ W1l,
    ushort_t* __restrict__ WLh, ushort_t* __restrict__ WLl,
    float* __restrict__ b0p, float* __restrict__ b1p)
{
  int id = blockIdx.x * 256 + threadIdx.x;
  if (id < 1048576) {
    int np = id >> 9, k = id & 511;
    int n = ((np & 3) << 9) | (np >> 2);
    float v = W0[n * 512 + k];
    ushort_t h = f2bf(v);
    W0h[id] = h; W0l[id] = f2bf(v - bf2f(h));
  } else if (id < 2097152) {
    int f = id - 1048576;
    int np = f >> 9, k = f & 511;
    int n = ((np & 3) << 9) | (np >> 2);
    float v = W1[n * 512 + k];
    ushort_t h = f2bf(v);
    W1h[f] = h; W1l[f] = f2bf(v - bf2f(h));
  } else if (id < 2359296) {
    int f = id - 2097152;
    float v = WL[f];
    ushort_t h = f2bf(v);
    WLh[f] = h; WLl[f] = f2bf(v - bf2f(h));
  } else if (id < 2361344) {
    int np = id - 2359296;
    int n = ((np & 3) << 9) | (np >> 2);
    b0p[np] = bi0[n] + bh0[n];
  } else if (id < 2363392) {
    int np = id - 2361344;
    int n = ((np & 3) << 9) | (np >> 2);
    b1p[np] = bi1[n] + bh1[n];
  }
}

// ---------------- gather: x = emb[ids], split to bf16 hi/lo ----------------
__global__ __launch_bounds__(256) void gather_kernel(
    const int* __restrict__ ids, const float* __restrict__ emb,
    ushort_t* __restrict__ Xh, ushort_t* __restrict__ Xl)
{
  int f = blockIdx.x * 256 + threadIdx.x;     // 65536*128 float4-chunks
  int tok = f >> 7, c4 = f & 127;
  int id = ids[tok];
  float4 v = ((const float4*)emb)[(size_t)id * 128 + c4];
  ushort_t h0 = f2bf(v.x), h1 = f2bf(v.y), h2 = f2bf(v.z), h3 = f2bf(v.w);
  ushort_t l0 = f2bf(v.x - bf2f(h0)), l1 = f2bf(v.y - bf2f(h1));
  ushort_t l2 = f2bf(v.z - bf2f(h2)), l3 = f2bf(v.w - bf2f(h3));
  uint2v hv = { (unsigned)h0 | ((unsigned)h1 << 16), (unsigned)h2 | ((unsigned)h3 << 16) };
  uint2v lv = { (unsigned)l0 | ((unsigned)l1 << 16), (unsigned)l2 | ((unsigned)l3 << 16) };
  *(uint2v*)(Xh + (size_t)f * 4) = hv;
  *(uint2v*)(Xl + (size_t)f * 4) = lv;
}

// ---------------- fused split-GEMM -----------------------------------------
// MODE 0: LSTM layer  -> h = sig(o)*tanh(sig(i)*tanh(g)), write h hi/lo bf16
// MODE 1: final linear -> out = relu(acc + bias), write fp32
template <int MODE>
__global__ __launch_bounds__(256, 2) void gemm_kernel(
    const ushort_t* __restrict__ Ah, const ushort_t* __restrict__ Al,
    const ushort_t* __restrict__ Bh, const ushort_t* __restrict__ Bl,
    const float* __restrict__ bias,
    ushort_t* __restrict__ Oh, ushort_t* __restrict__ Ol,
    float* __restrict__ Out, int nbShift, int nbMask)
{
  __shared__ __align__(16) ushort_t smem[16384];   // 32 KB
  ushort_t* sAh = smem;
  ushort_t* sAl = smem + 4096;
  ushort_t* sBh = smem + 8192;
  ushort_t* sBl = smem + 12288;

  const int T = threadIdx.x;
  const int lane = T & 63;
  const int wv = T >> 6;
  const int wrow = wv >> 1, wcol = wv & 1;
  const int mb = (int)blockIdx.x >> nbShift;
  const int nb = (int)blockIdx.x & nbMask;
  const size_t t0 = (size_t)mb * 128;
  const int n0 = nb * 128;

  // staging: chunk C covers LDS bytes C*16 (lane-contiguous, required by
  // global_load_lds). Global source q is XOR-swizzled by row to kill the
  // 8-way ds_read_b128 bank conflict (2-way is free).
  const int r0 = T >> 2, q0 = T & 3;
  const int qg = q0 ^ ((r0 >> 1) & 3);            // same for r0 and r0+64
  const int lo0 = T * 8, lo1 = T * 8 + 2048;      // halves
  const ushort_t* gAh0 = Ah + (t0 + r0) * 512 + qg * 8;
  const ushort_t* gAh1 = gAh0 + 64 * 512;
  const ushort_t* gAl0 = Al + (t0 + r0) * 512 + qg * 8;
  const ushort_t* gAl1 = gAl0 + 64 * 512;
  const ushort_t* gBh0 = Bh + (size_t)(n0 + r0) * 512 + qg * 8;
  const ushort_t* gBh1 = gBh0 + 64 * 512;
  const ushort_t* gBl0 = Bl + (size_t)(n0 + r0) * 512 + qg * 8;
  const ushort_t* gBl1 = gBl0 + 64 * 512;

  // fragment read offsets (iter-invariant)
  const int m_ = lane & 15, qf = lane >> 4;
  const int qs = qf ^ ((m_ >> 1) & 3);
  const int offA = wrow * 2048 + m_ * 32 + qs * 8;
  const int offB = wcol * 2048 + m_ * 32 + qs * 8;

  float4v acc[4][4];
#pragma unroll
  for (int i = 0; i < 4; ++i)
#pragma unroll
    for (int j = 0; j < 4; ++j)
      acc[i][j] = (float4v){0.f, 0.f, 0.f, 0.f};

  for (int it = 0; it < 16; ++it) {
    gl2lds16(gAh0, sAh + lo0);
    gl2lds16(gAh1, sAh + lo1);
    gl2lds16(gAl0, sAl + lo0);
    gl2lds16(gAl1, sAl + lo1);
    gl2lds16(gBh0, sBh + lo0);
    gl2lds16(gBh1, sBh + lo1);
    gl2lds16(gBl0, sBl + lo0);
    gl2lds16(gBl1, sBl + lo1);
    gAh0 += 32; gAh1 += 32; gAl0 += 32; gAl1 += 32;
    gBh0 += 32; gBh1 += 32; gBl0 += 32; gBl1 += 32;
    __syncthreads();

    short8 aH[4], aL[4], bH[4], bL[4];
#pragma unroll
    for (int i = 0; i < 4; ++i) {
      aH[i] = *(const short8*)(sAh + offA + i * 512);
      aL[i] = *(const short8*)(sAl + offA + i * 512);
      bH[i] = *(const short8*)(sBh + offB + i * 512);
      bL[i] = *(const short8*)(sBl + offB + i * 512);
    }
#pragma unroll
    for (int i = 0; i < 4; ++i)
#pragma unroll
      for (int j = 0; j < 4; ++j) {
        acc[i][j] = __builtin_amdgcn_mfma_f32_16x16x32_bf16(aH[i], bH[j], acc[i][j], 0, 0, 0);
        acc[i][j] = __builtin_amdgcn_mfma_f32_16x16x32_bf16(aL[i], bH[j], acc[i][j], 0, 0, 0);
        acc[i][j] = __builtin_amdgcn_mfma_f32_16x16x32_bf16(aH[i], bL[j], acc[i][j], 0, 0, 0);
      }
    __syncthreads();
  }

  if (MODE == 0) {
    float biasv[4];
#pragma unroll
    for (int j = 0; j < 4; ++j) biasv[j] = bias[n0 + wcol * 64 + j * 16 + m_];
    float* hT = (float*)smem;                  // 128 x 32, stride 33 (16.9 KB)
    const int g0 = lane & 3;                   // = gate index at this lane's col
    const int rowb = wrow * 64 + (qf << 2);
    const int ulb = (wcol * 64 + m_) >> 2;
#pragma unroll
    for (int i = 0; i < 4; ++i)
#pragma unroll
      for (int j = 0; j < 4; ++j)
#pragma unroll
        for (int r = 0; r < 4; ++r) {
          float e = acc[i][j][r] + biasv[j];
          float v1 = __shfl_xor(e, 1);
          float v2 = __shfl_xor(e, 2);
          float v3 = __shfl_xor(e, 3);
          // vals[m] = gate (g0^m); want gate G at vals[g0^G]; f unused.
          float iv = (g0 == 0) ? e  : (g0 == 1) ? v1 : (g0 == 2) ? v2 : v3;
          float gv = (g0 == 0) ? v2 : (g0 == 1) ? v3 : (g0 == 2) ? e  : v1;
          float ov = (g0 == 0) ? v3 : (g0 == 1) ? v2 : (g0 == 2) ? v1 : e;
          float cc = sigmoidf_(iv) * tanhf_(gv);
          float hh = sigmoidf_(ov) * tanhf_(cc);
          if (g0 == 0)
            hT[(rowb + i * 16 + r) * 33 + ulb + j * 4] = hh;
        }
    __syncthreads();
    const int tl = T >> 1, hf = T & 1;
    const float* src = hT + tl * 33 + hf * 16;
    unsigned int pH[8], pL[8];
#pragma unroll
    for (int k2 = 0; k2 < 8; ++k2) {
      float f0 = src[2 * k2], f1 = src[2 * k2 + 1];
      ushort_t h0_ = f2bf(f0), h1_ = f2bf(f1);
      ushort_t l0_ = f2bf(f0 - bf2f(h0_)), l1_ = f2bf(f1 - bf2f(h1_));
      pH[k2] = (unsigned)h0_ | ((unsigned)h1_ << 16);
      pL[k2] = (unsigned)l0_ | ((unsigned)l1_ << 16);
    }
    size_t base = (t0 + tl) * 512 + (size_t)(nb * 32) + hf * 16;
    *(uint4v*)(Oh + base)     = (uint4v){pH[0], pH[1], pH[2], pH[3]};
    *(uint4v*)(Oh + base + 8) = (uint4v){pH[4], pH[5], pH[6], pH[7]};
    *(uint4v*)(Ol + base)     = (uint4v){pL[0], pL[1], pL[2], pL[3]};
    *(uint4v*)(Ol + base + 8) = (uint4v){pL[4], pL[5], pL[6], pL[7]};
  } else {
    float biasv[4];
#pragma unroll
    for (int j = 0; j < 4; ++j) biasv[j] = bias[n0 + wcol * 64 + j * 16 + m_];
#pragma unroll
    for (int i = 0; i < 4; ++i)
#pragma unroll
      for (int j = 0; j < 4; ++j)
#pragma unroll
        for (int r = 0; r < 4; ++r) {
          float v = acc[i][j][r] + biasv[j];
          v = fmaxf(v, 0.0f);
          size_t row = t0 + wrow * 64 + i * 16 + qf * 4 + r;
          Out[row * 512 + (size_t)(n0 + wcol * 64 + j * 16 + m_)] = v;
        }
  }
}

extern "C" void kernel_launch(void* const* d_in, const int* in_sizes, int n_in,
                              void* d_out, int out_size, void* d_ws, size_t ws_size,
                              hipStream_t stream) {
  (void)in_sizes; (void)n_in; (void)out_size; (void)ws_size;
  const int*   ids   = (const int*)d_in[0];
  const float* emb   = (const float*)d_in[1];
  const float* W0    = (const float*)d_in[2];
  // d_in[3] = W_hh0 unused (h_prev = 0)
  const float* bi0   = (const float*)d_in[4];
  const float* bh0   = (const float*)d_in[5];
  const float* W1    = (const float*)d_in[6];
  // d_in[7] = W_hh1 unused
  const float* bi1   = (const float*)d_in[8];
  const float* bh1   = (const float*)d_in[9];
  const float* WL    = (const float*)d_in[10];
  const float* blin  = (const float*)d_in[11];
  float* out = (float*)d_out;

  char* ws = (char*)d_ws;
  const size_t MB = 1024 * 1024;
  ushort_t* W0h = (ushort_t*)(ws);
  ushort_t* W0l = (ushort_t*)(ws + 2 * MB);
  ushort_t* W1h = (ushort_t*)(ws + 4 * MB);
  ushort_t* W1l = (ushort_t*)(ws + 6 * MB);
  ushort_t* WLh = (ushort_t*)(ws + 8 * MB);
  ushort_t* WLl = (ushort_t*)(ws + 8 * MB + 512 * 1024);
  float*    b0p = (float*)(ws + 9 * MB);
  float*    b1p = (float*)(ws + 9 * MB + 8192);
  ushort_t* Xh  = (ushort_t*)(ws + 16 * MB);
  ushort_t* Xl  = (ushort_t*)(ws + 80 * MB);
  ushort_t* H0h = (ushort_t*)(ws + 144 * MB);
  ushort_t* H0l = (ushort_t*)(ws + 208 * MB);
  ushort_t* H1h = Xh;   // x dead after layer 0 — alias
  ushort_t* H1l = Xl;

  prep_kernel<<<9232, 256, 0, stream>>>(W0, bi0, bh0, W1, bi1, bh1, WL,
                                        W0h, W0l, W1h, W1l, WLh, WLl, b0p, b1p);
  gather_kernel<<<32768, 256, 0, stream>>>(ids, emb, Xh, Xl);
  gemm_kernel<0><<<8192, 256, 0, stream>>>(Xh, Xl, W0h, W0l, b0p, H0h, H0l, nullptr, 4, 15);
  gemm_kernel<0><<<8192, 256, 0, stream>>>(H0h, H0l, W1h, W1l, b1p, H1h, H1l, nullptr, 4, 15);
  gemm_kernel<1><<<2048, 256, 0, stream>>>(H1h, H1l, WLh, WLl, blin, nullptr, nullptr, out, 2, 3);
}

// Round 2
// 1112.762 us; speedup vs baseline: 1.1620x; 1.1620x over previous
//
#include <hip/hip_runtime.h>
#include <stdint.h>

// LSTM2Encoder: x=emb[ids]; h0=lstm0(x); h1=lstm1(h0); out=relu(h1@Wlin^T+b)
// GEMMs via bf16 hi/lo 3-product split MFMA. Gate rows (i,f,g,o)-interleaved;
// epilogue uses an in-register 4x4 lane<->reg transpose so each lane computes
// the sigmoid/tanh chain exactly once (R1 had 4x redundant transcendentals).
// Tile 256x128, 512 threads (8 waves, 4x2), BK=32, global_load_lds staging.

typedef unsigned short ushort_t;
typedef __attribute__((ext_vector_type(8))) short short8;
typedef __attribute__((ext_vector_type(4))) float float4v;
typedef __attribute__((ext_vector_type(4))) unsigned int uint4v;
typedef __attribute__((ext_vector_type(2))) unsigned int uint2v;

__device__ __forceinline__ ushort_t f2bf(float x) {
  union { float f; unsigned int u; } a; a.f = x;
  unsigned int r = a.u + 0x7fffu + ((a.u >> 16) & 1u);
  return (ushort_t)(r >> 16);
}
__device__ __forceinline__ float bf2f(ushort_t h) {
  union { unsigned int u; float f; } a; a.u = ((unsigned int)h) << 16;
  return a.f;
}
__device__ __forceinline__ float sigmoidf_(float x) { return 1.0f / (1.0f + __expf(-x)); }
__device__ __forceinline__ float tanhf_(float x) { return 1.0f - 2.0f / (__expf(2.0f * x) + 1.0f); }

__device__ __forceinline__ void gl2lds16(const void* g, void* l) {
  __builtin_amdgcn_global_load_lds(
      (const __attribute__((address_space(1))) void*)g,
      (__attribute__((address_space(3))) void*)l, 16, 0, 0);
}

// ---------------- prep: permute+split weights, fold biases -----------------
// W'[4j+g][k] = W[g*512+j][k]  (g in {i,f,g,o});  b'[4j+g] = b_ih[n]+b_hh[n]
__global__ __launch_bounds__(256) void prep_kernel(
    const float* __restrict__ W0, const float* __restrict__ bi0, const float* __restrict__ bh0,
    const float* __restrict__ W1, const float* __restrict__ bi1, const float* __restrict__ bh1,
    const float* __restrict__ WL,
    ushort_t* __restrict__ W0h, ushort_t* __restrict__ W0l,
    ushort_t* __restrict__ W1h, ushort_t* __restrict__ W1l,
    ushort_t* __restrict__ WLh, ushort_t* __restrict__ WLl,
    float* __restrict__ b0p, float* __restrict__ b1p)
{
  int id = blockIdx.x * 256 + threadIdx.x;
  if (id < 1048576) {
    int np = id >> 9, k = id & 511;
    int n = ((np & 3) << 9) | (np >> 2);
    float v = W0[n * 512 + k];
    ushort_t h = f2bf(v);
    W0h[id] = h; W0l[id] = f2bf(v - bf2f(h));
  } else if (id < 2097152) {
    int f = id - 1048576;
    int np = f >> 9, k = f & 511;
    int n = ((np & 3) << 9) | (np >> 2);
    float v = W1[n * 512 + k];
    ushort_t h = f2bf(v);
    W1h[f] = h; W1l[f] = f2bf(v - bf2f(h));
  } else if (id < 2359296) {
    int f = id - 2097152;
    float v = WL[f];
    ushort_t h = f2bf(v);
    WLh[f] = h; WLl[f] = f2bf(v - bf2f(h));
  } else if (id < 2361344) {
    int np = id - 2359296;
    int n = ((np & 3) << 9) | (np >> 2);
    b0p[np] = bi0[n] + bh0[n];
  } else if (id < 2363392) {
    int np = id - 2361344;
    int n = ((np & 3) << 9) | (np >> 2);
    b1p[np] = bi1[n] + bh1[n];
  }
}

// ---------------- gather: x = emb[ids], split to bf16 hi/lo ----------------
__global__ __launch_bounds__(256) void gather_kernel(
    const int* __restrict__ ids, const float* __restrict__ emb,
    ushort_t* __restrict__ Xh, ushort_t* __restrict__ Xl)
{
  int f = blockIdx.x * 256 + threadIdx.x;     // 65536*128 float4-chunks
  int tok = f >> 7, c4 = f & 127;
  int id = ids[tok];
  float4 v = ((const float4*)emb)[(size_t)id * 128 + c4];
  ushort_t h0 = f2bf(v.x), h1 = f2bf(v.y), h2 = f2bf(v.z), h3 = f2bf(v.w);
  ushort_t l0 = f2bf(v.x - bf2f(h0)), l1 = f2bf(v.y - bf2f(h1));
  ushort_t l2 = f2bf(v.z - bf2f(h2)), l3 = f2bf(v.w - bf2f(h3));
  uint2v hv = { (unsigned)h0 | ((unsigned)h1 << 16), (unsigned)h2 | ((unsigned)h3 << 16) };
  uint2v lv = { (unsigned)l0 | ((unsigned)l1 << 16), (unsigned)l2 | ((unsigned)l3 << 16) };
  *(uint2v*)(Xh + (size_t)f * 4) = hv;
  *(uint2v*)(Xl + (size_t)f * 4) = lv;
}

// ---------------- fused split-GEMM, 256x128 tile ---------------------------
// MODE 0: LSTM layer  -> h = sig(o)*tanh(sig(i)*tanh(g)), write h hi/lo bf16
// MODE 1: final linear -> out = relu(acc + bias), write fp32
template <int MODE>
__global__ __launch_bounds__(512, 4) void gemm_kernel(
    const ushort_t* __restrict__ Ah, const ushort_t* __restrict__ Al,
    const ushort_t* __restrict__ Bh, const ushort_t* __restrict__ Bl,
    const float* __restrict__ bias,
    ushort_t* __restrict__ Oh, ushort_t* __restrict__ Ol,
    float* __restrict__ Out, int nbShift, int nbMask)
{
  __shared__ __align__(16) ushort_t smem[24576];   // 48 KB
  ushort_t* sAh = smem;            // 256 rows x 32 k  (8192)
  ushort_t* sAl = smem + 8192;
  ushort_t* sBh = smem + 16384;    // 128 rows x 32 k  (4096)
  ushort_t* sBl = smem + 20480;

  const int T = threadIdx.x;       // 0..511
  const int lane = T & 63;
  const int wv = T >> 6;           // 0..7
  const int wrow = wv >> 1, wcol = wv & 1;    // 4 x 2 wave grid
  const int mb = (int)blockIdx.x >> nbShift;
  const int nb = (int)blockIdx.x & nbMask;
  const size_t t0 = (size_t)mb * 256;
  const int n0 = nb * 128;

  // staging: thread T stages LDS chunk C at bytes C*16 (lane-contiguous, as
  // global_load_lds requires). Global k-quad is XOR-swizzled by row so the
  // ds_read_b128 fragment reads land 2-way (free) instead of 8-way.
  const int r0 = T >> 2;                          // 0..127
  const int qg = (T & 3) ^ ((r0 >> 1) & 3);
  const int lo = T * 8;                           // ushort index = T*16 bytes
  const ushort_t* gAh = Ah + (t0 + r0) * 512 + qg * 8;   // rows 0..127; +128 via +65536
  const ushort_t* gAl = Al + (t0 + r0) * 512 + qg * 8;
  const ushort_t* gBh = Bh + (size_t)(n0 + r0) * 512 + qg * 8;
  const ushort_t* gBl = Bl + (size_t)(n0 + r0) * 512 + qg * 8;

  // fragment read offsets (iter-invariant); un-swizzle with qs
  const int m_ = lane & 15, qf = lane >> 4;
  const int qs = qf ^ ((m_ >> 1) & 3);
  const int offA = wrow * 2048 + m_ * 32 + qs * 8;
  const int offB = wcol * 2048 + m_ * 32 + qs * 8;

  float4v acc[4][4];
#pragma unroll
  for (int i = 0; i < 4; ++i)
#pragma unroll
    for (int j = 0; j < 4; ++j)
      acc[i][j] = (float4v){0.f, 0.f, 0.f, 0.f};

  for (int it = 0; it < 16; ++it) {
    gl2lds16(gAh, sAh + lo);
    gl2lds16(gAh + 65536, sAh + lo + 4096);   // rows 128..255
    gl2lds16(gAl, sAl + lo);
    gl2lds16(gAl + 65536, sAl + lo + 4096);
    gl2lds16(gBh, sBh + lo);
    gl2lds16(gBl, sBl + lo);
    gAh += 32; gAl += 32; gBh += 32; gBl += 32;
    __syncthreads();

    short8 aH[4], aL[4], bH[4], bL[4];
#pragma unroll
    for (int i = 0; i < 4; ++i) {
      aH[i] = *(const short8*)(sAh + offA + i * 512);
      aL[i] = *(const short8*)(sAl + offA + i * 512);
      bH[i] = *(const short8*)(sBh + offB + i * 512);
      bL[i] = *(const short8*)(sBl + offB + i * 512);
    }
#pragma unroll
    for (int i = 0; i < 4; ++i)
#pragma unroll
      for (int j = 0; j < 4; ++j) {
        acc[i][j] = __builtin_amdgcn_mfma_f32_16x16x32_bf16(aH[i], bH[j], acc[i][j], 0, 0, 0);
        acc[i][j] = __builtin_amdgcn_mfma_f32_16x16x32_bf16(aL[i], bH[j], acc[i][j], 0, 0, 0);
        acc[i][j] = __builtin_amdgcn_mfma_f32_16x16x32_bf16(aH[i], bL[j], acc[i][j], 0, 0, 0);
      }
    __syncthreads();
  }

  if (MODE == 0) {
    float biasv[4];
#pragma unroll
    for (int j = 0; j < 4; ++j) biasv[j] = bias[n0 + wcol * 64 + j * 16 + m_];
    float* hT = (float*)smem;                  // 256 x 32, stride 34 (34.8 KB)
    const bool b0 = (lane & 1) != 0;
    const bool b1 = (lane & 2) != 0;
    const int rowb = wrow * 64 + qf * 4 + (lane & 3);   // + i*16
    const int ub = wcol * 16 + (m_ >> 2);               // + j*4
#pragma unroll
    for (int i = 0; i < 4; ++i)
#pragma unroll
      for (int j = 0; j < 4; ++j) {
        // 4x4 lane<->reg transpose within each gate-quad: after this, lane
        // (base+r) holds gates i,f,g,o of row rowb+i*16 (distinct per lane).
        float e0 = acc[i][j][0] + biasv[j];
        float e1 = acc[i][j][1] + biasv[j];
        float e2 = acc[i][j][2] + biasv[j];
        float e3 = acc[i][j][3] + biasv[j];
        float ta = __shfl_xor(b0 ? e0 : e1, 1);
        float tb = __shfl_xor(b0 ? e2 : e3, 1);
        float z0 = b0 ? ta : e0, z1 = b0 ? e1 : ta;
        float z2 = b0 ? tb : e2, z3 = b0 ? e3 : tb;
        float ua = __shfl_xor(b1 ? z0 : z2, 2);
        float ub_ = __shfl_xor(b1 ? z1 : z3, 2);
        float yi = b1 ? ua : z0;                 // gate i
        float yg = b1 ? z2 : ua;                 // gate g   (y1 = f unused)
        float yo = b1 ? z3 : ub_;                // gate o
        float cc = sigmoidf_(yi) * tanhf_(yg);
        float hh = sigmoidf_(yo) * tanhf_(cc);
        hT[(rowb + i * 16) * 34 + ub + j * 4] = hh;
      }
    __syncthreads();
    const int tl = T >> 1, hf = T & 1;
    const float* src = hT + tl * 34 + hf * 16;
    unsigned int pH[8], pL[8];
#pragma unroll
    for (int k2 = 0; k2 < 8; ++k2) {
      float f0 = src[2 * k2], f1 = src[2 * k2 + 1];
      ushort_t h0_ = f2bf(f0), h1_ = f2bf(f1);
      ushort_t l0_ = f2bf(f0 - bf2f(h0_)), l1_ = f2bf(f1 - bf2f(h1_));
      pH[k2] = (unsigned)h0_ | ((unsigned)h1_ << 16);
      pL[k2] = (unsigned)l0_ | ((unsigned)l1_ << 16);
    }
    size_t base = (t0 + tl) * 512 + (size_t)(nb * 32) + hf * 16;
    *(uint4v*)(Oh + base)     = (uint4v){pH[0], pH[1], pH[2], pH[3]};
    *(uint4v*)(Oh + base + 8) = (uint4v){pH[4], pH[5], pH[6], pH[7]};
    *(uint4v*)(Ol + base)     = (uint4v){pL[0], pL[1], pL[2], pL[3]};
    *(uint4v*)(Ol + base + 8) = (uint4v){pL[4], pL[5], pL[6], pL[7]};
  } else {
    float biasv[4];
#pragma unroll
    for (int j = 0; j < 4; ++j) biasv[j] = bias[n0 + wcol * 64 + j * 16 + m_];
#pragma unroll
    for (int i = 0; i < 4; ++i)
#pragma unroll
      for (int j = 0; j < 4; ++j)
#pragma unroll
        for (int r = 0; r < 4; ++r) {
          float v = acc[i][j][r] + biasv[j];
          v = fmaxf(v, 0.0f);
          size_t row = t0 + wrow * 64 + i * 16 + qf * 4 + r;
          Out[row * 512 + (size_t)(n0 + wcol * 64 + j * 16 + m_)] = v;
        }
  }
}

extern "C" void kernel_launch(void* const* d_in, const int* in_sizes, int n_in,
                              void* d_out, int out_size, void* d_ws, size_t ws_size,
                              hipStream_t stream) {
  (void)in_sizes; (void)n_in; (void)out_size; (void)ws_size;
  const int*   ids   = (const int*)d_in[0];
  const float* emb   = (const float*)d_in[1];
  const float* W0    = (const float*)d_in[2];
  // d_in[3] = W_hh0 unused (h_prev = 0)
  const float* bi0   = (const float*)d_in[4];
  const float* bh0   = (const float*)d_in[5];
  const float* W1    = (const float*)d_in[6];
  // d_in[7] = W_hh1 unused
  const float* bi1   = (const float*)d_in[8];
  const float* bh1   = (const float*)d_in[9];
  const float* WL    = (const float*)d_in[10];
  const float* blin  = (const float*)d_in[11];
  float* out = (float*)d_out;

  char* ws = (char*)d_ws;
  const size_t MB = 1024 * 1024;
  ushort_t* W0h = (ushort_t*)(ws);
  ushort_t* W0l = (ushort_t*)(ws + 2 * MB);
  ushort_t* W1h = (ushort_t*)(ws + 4 * MB);
  ushort_t* W1l = (ushort_t*)(ws + 6 * MB);
  ushort_t* WLh = (ushort_t*)(ws + 8 * MB);
  ushort_t* WLl = (ushort_t*)(ws + 8 * MB + 512 * 1024);
  float*    b0p = (float*)(ws + 9 * MB);
  float*    b1p = (float*)(ws + 9 * MB + 8192);
  ushort_t* Xh  = (ushort_t*)(ws + 16 * MB);
  ushort_t* Xl  = (ushort_t*)(ws + 80 * MB);
  ushort_t* H0h = (ushort_t*)(ws + 144 * MB);
  ushort_t* H0l = (ushort_t*)(ws + 208 * MB);
  ushort_t* H1h = Xh;   // x dead after layer 0 — alias
  ushort_t* H1l = Xl;

  prep_kernel<<<9232, 256, 0, stream>>>(W0, bi0, bh0, W1, bi1, bh1, WL,
                                        W0h, W0l, W1h, W1l, WLh, WLl, b0p, b1p);
  gather_kernel<<<32768, 256, 0, stream>>>(ids, emb, Xh, Xl);
  gemm_kernel<0><<<4096, 512, 0, stream>>>(Xh, Xl, W0h, W0l, b0p, H0h, H0l, nullptr, 4, 15);
  gemm_kernel<0><<<4096, 512, 0, stream>>>(H0h, H0l, W1h, W1l, b1p, H1h, H1l, nullptr, 4, 15);
  gemm_kernel<1><<<1024, 512, 0, stream>>>(H1h, H1l, WLh, WLl, blin, nullptr, nullptr, out, 2, 3);
}